// Round 9
// baseline (4537.651 us; speedup 1.0000x reference)
//
#include <hip/hip_runtime.h>

#define B_ 64
#define T_ 512
#define I_ 512
#define H_ 1024
#define FPAD 16       // pad flags to 64 B lines
#define TPS 16384     // shorts per team plane (16 rows x 1024 cols)
#define NWG 256       // 4 teams x 64 WGs (1 wave each)
#define PAIRB 65536   // bytes per plane pair (hi 32 KB + lo 32 KB)
#define NDEPTH 4      // plane-ring depth (pair index = s & 3)
#define TEAMB (NDEPTH * PAIRB)
#define TAGM 0x8000800080008000ULL

typedef __attribute__((ext_vector_type(8))) short bf16x8;
typedef __attribute__((ext_vector_type(4))) float f32x4;

static __device__ __forceinline__ short f2bf(float f) {
  unsigned u = __float_as_uint(f);
  unsigned r = (u + 0x7fffu + ((u >> 16) & 1u)) >> 16;  // RNE
  return (short)(unsigned short)r;
}
static __device__ __forceinline__ float bf2f(short s) {
  return __uint_as_float(((unsigned)(unsigned short)s) << 16);
}
static __device__ __forceinline__ bf16x8 pack8(float4 u, float4 v) {
  bf16x8 r;
  r[0] = f2bf(u.x); r[1] = f2bf(u.y); r[2] = f2bf(u.z); r[3] = f2bf(u.w);
  r[4] = f2bf(v.x); r[5] = f2bf(v.y); r[6] = f2bf(v.z); r[7] = f2bf(v.w);
  return r;
}

// ---------------------------------------------------------------------------
// Kernel 1 (unchanged): pre = x @ Wi^T + bi + bh, in-place into d_out.
// ---------------------------------------------------------------------------
#define PBK 32
#define PLDA 40

__global__ __launch_bounds__(256) void proj_gemm(
    const float* __restrict__ x, const float* __restrict__ Wi,
    const float* __restrict__ bi, const float* __restrict__ bh,
    float* __restrict__ out) {
  __shared__ short As[128 * PLDA];
  __shared__ short Bs[128 * PLDA];
  const int tid = threadIdx.x;
  const int m0 = (blockIdx.x >> 3) * 128;
  const int n0 = (blockIdx.x & 7) * 128;
  const int wave = tid >> 6, lane = tid & 63;
  const int wm = (wave & 1) * 64, wn = (wave >> 1) * 64;
  const int lm = lane & 15, lq = lane >> 4;

  f32x4 acc[4][4];
#pragma unroll
  for (int i = 0; i < 4; ++i)
#pragma unroll
    for (int j = 0; j < 4; ++j) {
      f32x4 z = {0.f, 0.f, 0.f, 0.f};
      acc[i][j] = z;
    }

  const int lrow = tid >> 1;
  const int lcol = (tid & 1) * 16;
  const float* xp = x + (size_t)(m0 + lrow) * I_ + lcol;
  const float* wp = Wi + (size_t)(n0 + lrow) * I_ + lcol;

  for (int k0 = 0; k0 < I_; k0 += PBK) {
    float4 a0 = *(const float4*)(xp + k0);
    float4 a1 = *(const float4*)(xp + k0 + 4);
    float4 a2 = *(const float4*)(xp + k0 + 8);
    float4 a3 = *(const float4*)(xp + k0 + 12);
    float4 b0 = *(const float4*)(wp + k0);
    float4 b1 = *(const float4*)(wp + k0 + 4);
    float4 b2 = *(const float4*)(wp + k0 + 8);
    float4 b3 = *(const float4*)(wp + k0 + 12);
    __syncthreads();
    *(bf16x8*)&As[lrow * PLDA + lcol] = pack8(a0, a1);
    *(bf16x8*)&As[lrow * PLDA + lcol + 8] = pack8(a2, a3);
    *(bf16x8*)&Bs[lrow * PLDA + lcol] = pack8(b0, b1);
    *(bf16x8*)&Bs[lrow * PLDA + lcol + 8] = pack8(b2, b3);
    __syncthreads();

    bf16x8 af[4], bfr[4];
#pragma unroll
    for (int i = 0; i < 4; ++i)
      af[i] = *(const bf16x8*)&As[(wm + i * 16 + lm) * PLDA + lq * 8];
#pragma unroll
    for (int j = 0; j < 4; ++j)
      bfr[j] = *(const bf16x8*)&Bs[(wn + j * 16 + lm) * PLDA + lq * 8];
#pragma unroll
    for (int i = 0; i < 4; ++i)
#pragma unroll
      for (int j = 0; j < 4; ++j)
        acc[i][j] = __builtin_amdgcn_mfma_f32_16x16x32_bf16(af[i], bfr[j],
                                                            acc[i][j], 0, 0, 0);
  }

  const int rb = m0 + wm + lq * 4;
  const int cb = n0 + wn + lm;
#pragma unroll
  for (int j = 0; j < 4; ++j) {
    const int n = cb + j * 16;
    const float bias = bi[n] + bh[n];
#pragma unroll
    for (int i = 0; i < 4; ++i) {
      const int m = rb + i * 16;
#pragma unroll
      for (int r = 0; r < 4; ++r)
        out[(size_t)(m + r) * H_ + n] = acc[i][j][r] + bias;
    }
  }
}

// ---------------------------------------------------------------------------
// Agent-scope (L3-coherent) helpers.
// ---------------------------------------------------------------------------
static __device__ __forceinline__ unsigned long long ld_a8(const void* p) {
  return __hip_atomic_load((const unsigned long long*)p, __ATOMIC_RELAXED,
                           __HIP_MEMORY_SCOPE_AGENT);
}
static __device__ __forceinline__ void st_a2(unsigned short* p,
                                             unsigned short v) {
  __hip_atomic_store(p, v, __ATOMIC_RELAXED, __HIP_MEMORY_SCOPE_AGENT);
}
static __device__ __forceinline__ int ld_flag(const int* p) {
  return __hip_atomic_load(p, __ATOMIC_RELAXED, __HIP_MEMORY_SCOPE_AGENT);
}

union frag_u {
  unsigned long long q[2];
  bf16x8 v;
};

// ---------------------------------------------------------------------------
// Kernel 2 (R9 = single-wave WGs: zero barriers, zero LDS, zero packing).
//
// R8 post-mortem: the 4-wave k-split forced an LDS reduce + pack + two
// __syncthreads + wave-0 assemble into EVERY step (~1-1.5 us of intra-WG
// convergence) -- none of it removable while waves split k. R9: one wave per
// WG (256 WGs x 64 thr). WG w of team t computes its full 16 rows x 16 cols
// with k=1024 (32 blocks, 96 MFMAs -- same per-team MFMA total as R8).
//
// Per step per wave:
//  1. sentinel spin, SLEEP-FREE (64 B/wave/round; lane l samples 8 B of block
//     l>>1 at offset (l&1)*512 -- 2 samples/block covering both producers of
//     that block; one __all covers all 32 blocks).
//  2. depth-12 rolling fetch: issue 12 blocks (32 B/lane each hi+lo), write
//     gate poll overlaps the RT, then consume 32 blocks: per-block tag verify
//     (rare-stale respin, backstop), 3 MFMAs, refill slot with block i+12.
//     12 outstanding loads stream back-to-back after the first RT.
//  3. v = pre +/- rs, ReLU; 8 scattered 2 B tagged stores (R5/R6: scattered
//     ~= coalesced, so no pack stage); flag posts right after the consume
//     loop (drain-free: MFMA issue proves loads retired -- R7 semantics).
//
// Protocol otherwise identical to R8 (proven): sign-bit generation tags
// (ReLU => h>=0; hi=TRUNC => lo>=0), tag(s)=(s>>2)&1, tag=1 steps store
// negated values & consumers compute v = pre - sum; NDEPTH=4 ring; write
// gate flags >= s-3 bounds skew <= 3 (tag aliasing at distance 4
// unreachable); h_0 zeros (tag 0) + flag=0 startup; 0xAA poison sign=1 is
// rejected by TR=0 checks, negative flags block the write gate.
// Deadlock-free: global-min-step WG's producers have issued their stores
// (eventually visible -> sentinels pass) and its write gate is satisfied.
// ---------------------------------------------------------------------------
__global__ __launch_bounds__(64, 1) void rnn_rec(
    const float* __restrict__ Wh, float* __restrict__ out,
    char* __restrict__ planes, int* __restrict__ flags) {
  const int lane = threadIdx.x;
  const int wg = blockIdx.x;
  const int team = wg >> 6;
  const int w = wg & 63;
  const int lm = lane & 15, lq = lane >> 4;

  // --- B-frags (full k): Bh[i] holds km=(w+i)&31; lane (lq,lm) holds
  // Wh[16w+lm][km*32 + lq*8 + j], j=0..7. 64 frags = 256 VGPRs.
  bf16x8 Bh[32], Bl[32];
  {
    const float* wrow = Wh + (size_t)(16 * w + lm) * H_ + lq * 8;
#pragma unroll
    for (int i = 0; i < 32; ++i) {
      const int km = (w + i) & 31;
      float4 w0 = *(const float4*)(wrow + km * 32);
      float4 w1 = *(const float4*)(wrow + km * 32 + 4);
      float wf[8] = {w0.x, w0.y, w0.z, w0.w, w1.x, w1.y, w1.z, w1.w};
      bf16x8 hi, lo;
#pragma unroll
      for (int j = 0; j < 8; ++j) {
        hi[j] = f2bf(wf[j]);
        lo[j] = f2bf(wf[j] - bf2f(hi[j]));
      }
      Bh[i] = hi;
      Bl[i] = lo;
    }
  }

  char* tbase = planes + (size_t)team * TEAMB;
  const int* fwr = flags + (team * 64 + lane) * FPAD;  // write gate (64 fan-in)
  const int fown = wg * FPAD;

  // sentinel: lane l samples block l>>1, byte (l&1)*512 within its 1 KB hi-row
  const int soff = (lane >> 1) * 1024 + (lane & 1) * 512;

  // output/D-layout: lane holds D[m][n] m=(lane>>4)*4+reg, n=lane&15.
  const int cl = lm;                 // col within WG
  const int rb0 = lq * 4;            // first of 4 rows
  const int c = 16 * w + cl;         // global h col
  // short idx of h[r][c] in a plane: 256w + (cl>>3)*128 + r*8 + (cl&7)
  const int Sb = 256 * w + (cl >> 3) * 128 + (cl & 7);

  // --- startup: zero own h_0 slots (pair 0, tag 0, 4 rows hi+lo); flag=0.
  {
    unsigned short* p0 = (unsigned short*)tbase;
#pragma unroll
    for (int rr = 0; rr < 4; ++rr) {
      st_a2(p0 + Sb + (rb0 + rr) * 8, 0);
      st_a2(p0 + TPS + Sb + (rb0 + rr) * 8, 0);
    }
  }
  if (lane == 0)
    __hip_atomic_store(&flags[fown], 0, __ATOMIC_RELAXED,
                       __HIP_MEMORY_SCOPE_AGENT);

  float* outH = out + (size_t)B_ * T_ * H_;

  for (int s = 1; s <= T_; ++s) {
    const int t = s - 1;
    const int TR = ((s - 1) >> 2) & 1;               // expected tag of h_{s-1}
    const unsigned short flip = (unsigned short)(((s >> 2) & 1) << 15);
    const char* src = tbase + (size_t)((s - 1) & 3) * PAIRB;

    // pre loads issued early (consumed at v-compute)
    size_t oidx[4];
    float pre[4];
#pragma unroll
    for (int rr = 0; rr < 4; ++rr) {
      const int b = team * 16 + rb0 + rr;
      oidx[rr] = (size_t)b * (T_ * H_) + (size_t)t * H_ + c;
      pre[rr] = out[oidx[rr]];
    }

    // (1) sentinel spin, sleep-free: 64 B/wave/round, covers all 32 blocks
    for (;;) {
      const unsigned long long x = ld_a8(src + soff);
      const bool ok = TR ? ((x & TAGM) == TAGM) : ((x & TAGM) == 0ULL);
      if (__all(ok)) break;
    }

    // (2) issue first 12 blocks (depth-12 rolling pipeline)
    unsigned long long q[12][4];
#pragma unroll
    for (int i = 0; i < 12; ++i) {
      const char* p = src + (((w + i) & 31) * 1024) + lane * 16;
      q[i][0] = ld_a8(p);
      q[i][1] = ld_a8(p + 8);
      q[i][2] = ld_a8(p + 32768);      // lo plane
      q[i][3] = ld_a8(p + 32768 + 8);
    }

    // write gate (monotone; overlaps the fetch RT): all team flags >= s-3
    // => pair (s&3) readers (step s-3) retired => overwrite safe.
    const int need2 = s - 3;
    for (;;) {
      const int f = ld_flag(fwr);
      if (__all(f >= need2)) break;
      __builtin_amdgcn_s_sleep(1);
    }

    // (3) consume 32 blocks; per-block tag verify (rare respin); refill
    const f32x4 z = {0.f, 0.f, 0.f, 0.f};
    f32x4 c0 = z, c1 = z, c2 = z;
#pragma unroll
    for (int i = 0; i < 32; ++i) {
      const int sl = i % 12;
      for (;;) {
        const unsigned long long f =
            TR ? (q[sl][0] & q[sl][1] & q[sl][2] & q[sl][3])
               : (q[sl][0] | q[sl][1] | q[sl][2] | q[sl][3]);
        const bool ok = TR ? ((f & TAGM) == TAGM) : ((f & TAGM) == 0ULL);
        if (__all(ok)) break;
        __builtin_amdgcn_s_sleep(1);
        const char* p = src + (((w + i) & 31) * 1024) + lane * 16;
        q[sl][0] = ld_a8(p);
        q[sl][1] = ld_a8(p + 8);
        q[sl][2] = ld_a8(p + 32768);
        q[sl][3] = ld_a8(p + 32768 + 8);
      }
      frag_u ah, al;
      ah.q[0] = q[sl][0];
      ah.q[1] = q[sl][1];
      al.q[0] = q[sl][2];
      al.q[1] = q[sl][3];
      c0 = __builtin_amdgcn_mfma_f32_16x16x32_bf16(ah.v, Bh[i], c0, 0, 0, 0);
      c1 = __builtin_amdgcn_mfma_f32_16x16x32_bf16(ah.v, Bl[i], c1, 0, 0, 0);
      c2 = __builtin_amdgcn_mfma_f32_16x16x32_bf16(al.v, Bh[i], c2, 0, 0, 0);
      if (i < 20) {
        const char* p = src + (((w + i + 12) & 31) * 1024) + lane * 16;
        q[sl][0] = ld_a8(p);
        q[sl][1] = ld_a8(p + 8);
        q[sl][2] = ld_a8(p + 32768);
        q[sl][3] = ld_a8(p + 32768 + 8);
      }
    }

    // flag=s ASAP: all pair-((s-1)&3) loads retired (MFMA issue proves it).
    // Drain-free; unblocks producers' write gates early.
    if (lane == 0)
      __hip_atomic_store(&flags[fown], s, __ATOMIC_RELAXED,
                         __HIP_MEMORY_SCOPE_AGENT);

    const f32x4 rs = c0 + c1 + c2;
    unsigned short* dstH = (unsigned short*)(tbase + (size_t)(s & 3) * PAIRB);
#pragma unroll
    for (int rr = 0; rr < 4; ++rr) {
      float v = pre[rr] + (TR ? -rs[rr] : rs[rr]);  // TR=1 data was negated
      v = v > 0.f ? v : 0.f;
      // hi = TRUNC => lo = v - hi >= 0 => both sign bits free for the tag
      const unsigned short hv = (unsigned short)(__float_as_uint(v) >> 16);
      const float hf = __uint_as_float((unsigned)hv << 16);
      const unsigned short lv = (unsigned short)f2bf(v - hf);  // RNE, >= 0
      st_a2(dstH + Sb + (rb0 + rr) * 8, (unsigned short)(hv ^ flip));
      st_a2(dstH + TPS + Sb + (rb0 + rr) * 8, (unsigned short)(lv ^ flip));
      // out writes off the critical chain
      out[oidx[rr]] = v;
      if (s == T_) outH[(size_t)(team * 16 + rb0 + rr) * H_ + c] = v;
    }
  }
}

// ---------------------------------------------------------------------------
extern "C" void kernel_launch(void* const* d_in, const int* in_sizes, int n_in,
                              void* d_out, int out_size, void* d_ws,
                              size_t ws_size, hipStream_t stream) {
  const float* x = (const float*)d_in[0];   // [B,T,I]
  const float* Wi = (const float*)d_in[1];  // [H,I]
  const float* bi = (const float*)d_in[2];  // [H]
  const float* Wh = (const float*)d_in[3];  // [H,H]
  const float* bh = (const float*)d_in[4];  // [H]
  float* out = (float*)d_out;

  int* flags = (int*)d_ws;                       // 256 x 64 B = 16 KB
  char* planes = (char*)d_ws + 32768;            // 4 teams x 256 KB = 1 MB

  proj_gemm<<<2048, 256, 0, stream>>>(x, Wi, bi, bh, out);
  rnn_rec<<<NWG, 64, 0, stream>>>(Wh, out, planes, flags);
}